// Round 1
// baseline (1183.552 us; speedup 1.0000x reference)
//
#include <hip/hip_runtime.h>
#include <math.h>

#define KB_NUM 512
#define DIMC 64
#define BSZ 32
#define TLEN 4096
#define NTOK (BSZ * TLEN)          // 131072
#define DECAY_F 0.99f
#define EPS_F 1e-5f

// output offsets (flat f32, reference return order)
#define Q_OFF    ((size_t)0)
#define IDX_OFF  ((size_t)BSZ * DIMC * TLEN)        // 8388608
#define LOSS_OFF (IDX_OFF + (size_t)NTOK)           // 8519680
#define PLEX_OFF (LOSS_OFF + 1)                     // 8519681
#define NEMB_OFF (PLEX_OFF + 1)                     // 8519682
#define NCS_OFF  (NEMB_OFF + (size_t)KB_NUM * DIMC) // 8552450
#define NEA_OFF  (NCS_OFF + (size_t)KB_NUM)         // 8552962

// ---------------------------------------------------------------------------
// Kernel 0: 0.5 * ||e_k||^2 per code
// ---------------------------------------------------------------------------
__global__ void vq_enorm_kernel(const float* __restrict__ emb,
                                float* __restrict__ enorm) {
    int k = blockIdx.x * blockDim.x + threadIdx.x;
    if (k < KB_NUM) {
        const float4* e = (const float4*)(emb + (size_t)k * DIMC);
        float s = 0.f;
        #pragma unroll
        for (int i = 0; i < DIMC / 4; ++i) {
            float4 v = e[i];
            s += v.x * v.x + v.y * v.y + v.z * v.z + v.w * v.w;
        }
        enorm[k] = 0.5f * s;
    }
}

// ---------------------------------------------------------------------------
// Kernel 1: per-token argmin + quantize + loss partial + segment-sum atomics
// thread = one t; block = 256 threads; grid = (TLEN/256, BSZ)
// ---------------------------------------------------------------------------
__global__ __launch_bounds__(256) void vq_main_kernel(
    const float* __restrict__ z,
    const float* __restrict__ emb,
    const float* __restrict__ enorm,
    float* __restrict__ out,
    float* __restrict__ cnt,     // [R][KB_NUM]
    float* __restrict__ esum,    // [R][KB_NUM*DIMC]
    float* __restrict__ lossAcc, // [1]
    int R)
{
    const int b = blockIdx.y;
    const int t = blockIdx.x * 256 + threadIdx.x;

    // load this token's 64 channels; adjacent lanes -> adjacent t (coalesced)
    const float* zp = z + (size_t)b * (DIMC * TLEN) + t;
    float zr[DIMC];
    #pragma unroll
    for (int c = 0; c < DIMC; ++c) zr[c] = zp[(size_t)c * TLEN];

    // nearest code: argmin_k 0.5||e_k||^2 - z.e_k   (order == argmin d2)
    float best = 3.4e38f;
    int bidx = 0;
    for (int k = 0; k < KB_NUM; k += 2) {
        const float* __restrict__ e0 = emb + (size_t)k * DIMC;
        const float* __restrict__ e1 = e0 + DIMC;
        float a0 = 0.f, a1 = 0.f, a2 = 0.f, a3 = 0.f;
        float b0 = 0.f, b1 = 0.f, b2 = 0.f, b3 = 0.f;
        #pragma unroll
        for (int c = 0; c < DIMC; c += 4) {
            a0 = fmaf(zr[c    ], e0[c    ], a0);
            a1 = fmaf(zr[c + 1], e0[c + 1], a1);
            a2 = fmaf(zr[c + 2], e0[c + 2], a2);
            a3 = fmaf(zr[c + 3], e0[c + 3], a3);
            b0 = fmaf(zr[c    ], e1[c    ], b0);
            b1 = fmaf(zr[c + 1], e1[c + 1], b1);
            b2 = fmaf(zr[c + 2], e1[c + 2], b2);
            b3 = fmaf(zr[c + 3], e1[c + 3], b3);
        }
        float s0 = enorm[k]     - ((a0 + a1) + (a2 + a3));
        float s1 = enorm[k + 1] - ((b0 + b1) + (b2 + b3));
        if (s0 < best) { best = s0; bidx = k; }
        if (s1 < best) { best = s1; bidx = k + 1; }
    }

    // indices output (exact small int in f32)
    out[IDX_OFF + (size_t)b * TLEN + t] = (float)bidx;

    // quantized_st = z + (q - z), matching reference rounding; loss partial
    const float* __restrict__ eb = emb + (size_t)bidx * DIMC;
    float* qout = out + (size_t)b * (DIMC * TLEN) + t;
    float lsum = 0.f;
    #pragma unroll
    for (int c = 0; c < DIMC; ++c) {
        float q = eb[c];
        float d = q - zr[c];
        qout[(size_t)c * TLEN] = zr[c] + d;
        lsum = fmaf(d, d, lsum);
    }

    // segment sums via replicated atomics
    const int r = (int)((blockIdx.y * gridDim.x + blockIdx.x) % (unsigned)R);
    atomicAdd(cnt + (size_t)r * KB_NUM + bidx, 1.0f);
    float* es = esum + ((size_t)r * KB_NUM + bidx) * DIMC;
    #pragma unroll
    for (int c = 0; c < DIMC; ++c) atomicAdd(es + c, zr[c]);

    // wave-reduce loss, one atomic per wave
    #pragma unroll
    for (int off = 32; off > 0; off >>= 1)
        lsum += __shfl_down(lsum, off, 64);
    if ((threadIdx.x & 63) == 0) atomicAdd(lossAcc, lsum);
}

// ---------------------------------------------------------------------------
// Kernel 2: finalize — EMA updates, n_tot, perplexity, loss, new embedding
// single block of 512 threads (thread = code k)
// ---------------------------------------------------------------------------
__global__ __launch_bounds__(512) void vq_finalize_kernel(
    const float* __restrict__ cluster_size,
    const float* __restrict__ embed_avg,
    const float* __restrict__ cnt,
    const float* __restrict__ esum,
    const float* __restrict__ lossAcc,
    float* __restrict__ out, int R)
{
    const int k = threadIdx.x;

    float n = 0.f;
    for (int r = 0; r < R; ++r) n += cnt[(size_t)r * KB_NUM + k];

    float ncs = cluster_size[k] * DECAY_F + (1.0f - DECAY_F) * n;
    out[NCS_OFF + k] = ncs;

    __shared__ float red[KB_NUM];
    __shared__ float s_ntot;

    // n_tot = sum(new_cluster_size)
    red[k] = ncs;
    __syncthreads();
    for (int s = KB_NUM / 2; s > 0; s >>= 1) {
        if (k < s) red[k] += red[k + s];
        __syncthreads();
    }
    if (k == 0) s_ntot = red[0];
    __syncthreads();

    // perplexity over p = n/N
    float p = n * (1.0f / (float)NTOK);
    red[k] = p * logf(p + 1e-10f);
    __syncthreads();
    for (int s = KB_NUM / 2; s > 0; s >>= 1) {
        if (k < s) red[k] += red[k + s];
        __syncthreads();
    }
    if (k == 0) {
        out[PLEX_OFF] = expf(-red[0]);
        out[LOSS_OFF] = 0.25f * lossAcc[0] * (1.0f / (float)(BSZ * DIMC * TLEN));
    }
    __syncthreads();

    float ntot = s_ntot;
    float denom = (ncs + EPS_F) / (ntot + (float)KB_NUM * EPS_F) * ntot;

    for (int c = 0; c < DIMC; ++c) {
        float es = 0.f;
        for (int r = 0; r < R; ++r)
            es += esum[((size_t)r * KB_NUM + k) * DIMC + c];
        float nea = embed_avg[(size_t)k * DIMC + c] * DECAY_F + (1.0f - DECAY_F) * es;
        out[NEA_OFF + (size_t)k * DIMC + c] = nea;
        out[NEMB_OFF + (size_t)k * DIMC + c] = nea / denom;
    }
}

// ---------------------------------------------------------------------------
extern "C" void kernel_launch(void* const* d_in, const int* in_sizes, int n_in,
                              void* d_out, int out_size, void* d_ws, size_t ws_size,
                              hipStream_t stream)
{
    const float* z            = (const float*)d_in[0];
    const float* emb          = (const float*)d_in[1];
    const float* cluster_size = (const float*)d_in[2];
    const float* embed_avg    = (const float*)d_in[3];
    float* out = (float*)d_out;

    char* ws = (char*)d_ws;
    float* lossAcc = (float*)ws;            // 1 f32
    float* enorm   = (float*)(ws + 256);    // 512 f32
    const size_t CNT_OFF = 4096;
    const size_t perR = (size_t)(KB_NUM + KB_NUM * DIMC) * sizeof(float); // 133120 B

    int R = 1;
    if (ws_size > CNT_OFF + perR)
        R = (int)((ws_size - CNT_OFF) / perR);
    if (R < 1) R = 1;
    if (R > 16) R = 16;

    float* cnt  = (float*)(ws + CNT_OFF);          // [R][KB_NUM]
    float* esum = cnt + (size_t)R * KB_NUM;        // [R][KB_NUM*DIMC]

    // zero accumulators (lossAcc + cnt + esum); enorm is fully rewritten
    hipMemsetAsync(d_ws, 0, CNT_OFF + (size_t)R * perR, stream);

    vq_enorm_kernel<<<dim3(2), dim3(256), 0, stream>>>(emb, enorm);

    dim3 grid(TLEN / 256, BSZ);
    vq_main_kernel<<<grid, dim3(256), 0, stream>>>(z, emb, enorm, out,
                                                   cnt, esum, lossAcc, R);

    vq_finalize_kernel<<<dim3(1), dim3(512), 0, stream>>>(
        cluster_size, embed_avg, cnt, esum, lossAcc, out, R);
}

// Round 2
// 893.690 us; speedup vs baseline: 1.3243x; 1.3243x over previous
//
#include <hip/hip_runtime.h>
#include <math.h>

#define KB_NUM 512
#define DIMC 64
#define BSZ 32
#define TLEN 4096
#define NTOK (BSZ * TLEN)          // 131072
#define DECAY_F 0.99f
#define EPS_F 1e-5f
#define CHUNK_K 128                // codes staged in LDS per chunk (32 KB)

// output offsets (flat f32, reference return order)
#define Q_OFF    ((size_t)0)
#define IDX_OFF  ((size_t)BSZ * DIMC * TLEN)        // 8388608
#define LOSS_OFF (IDX_OFF + (size_t)NTOK)           // 8519680
#define PLEX_OFF (LOSS_OFF + 1)                     // 8519681
#define NEMB_OFF (PLEX_OFF + 1)                     // 8519682
#define NCS_OFF  (NEMB_OFF + (size_t)KB_NUM * DIMC) // 8552450
#define NEA_OFF  (NCS_OFF + (size_t)KB_NUM)         // 8552962

// ---------------------------------------------------------------------------
// Kernel 0: 0.5 * ||e_k||^2 per code
// ---------------------------------------------------------------------------
__global__ void vq_enorm_kernel(const float* __restrict__ emb,
                                float* __restrict__ enorm) {
    int k = blockIdx.x * blockDim.x + threadIdx.x;
    if (k < KB_NUM) {
        const float4* e = (const float4*)(emb + (size_t)k * DIMC);
        float s = 0.f;
        #pragma unroll
        for (int i = 0; i < DIMC / 4; ++i) {
            float4 v = e[i];
            s += v.x * v.x + v.y * v.y + v.z * v.z + v.w * v.w;
        }
        enorm[k] = 0.5f * s;
    }
}

// ---------------------------------------------------------------------------
// Kernel 1: per-token argmin + quantize + loss partial + segment-sum atomics
// thread = one t; block = 256 threads; grid = (TLEN/256, BSZ)
// Embedding staged in LDS chunks (broadcast reads); z held in VGPRs.
// ---------------------------------------------------------------------------
__global__ __launch_bounds__(256, 2) void vq_main_kernel(
    const float* __restrict__ z,
    const float* __restrict__ emb,
    const float* __restrict__ enorm,
    float* __restrict__ out,
    float* __restrict__ cnt,     // [R][KB_NUM]
    float* __restrict__ esum,    // [R][KB_NUM*DIMC]
    float* __restrict__ lossAcc, // [1]
    int R)
{
    __shared__ float se[CHUNK_K * DIMC];   // 32 KB embedding chunk
    __shared__ float sen[KB_NUM];          // 2 KB enorm table

    const int tid = threadIdx.x;
    const int b = blockIdx.y;
    const int t = blockIdx.x * 256 + tid;

    // stage enorm once (256 threads x 2)
    sen[tid]       = enorm[tid];
    sen[tid + 256] = enorm[tid + 256];

    // load this token's 64 channels; adjacent lanes -> adjacent t (coalesced)
    const float* zp = z + (size_t)b * (DIMC * TLEN) + t;
    float zr[DIMC];
    #pragma unroll
    for (int c = 0; c < DIMC; ++c) zr[c] = zp[(size_t)c * TLEN];

    float best = 3.4e38f;
    int bidx = 0;

    #pragma unroll 1
    for (int ch = 0; ch < KB_NUM / CHUNK_K; ++ch) {
        __syncthreads();
        // cooperative stage: 128 codes * 64 ch = 8192 f32 = 2048 float4
        const float4* src = (const float4*)(emb + (size_t)ch * CHUNK_K * DIMC);
        float4* dst = (float4*)se;
        #pragma unroll
        for (int j = 0; j < (CHUNK_K * DIMC / 4) / 256; ++j)
            dst[j * 256 + tid] = src[j * 256 + tid];
        __syncthreads();

        #pragma unroll 1
        for (int kk = 0; kk < CHUNK_K; kk += 2) {
            const float* __restrict__ e0 = se + kk * DIMC;
            const float* __restrict__ e1 = e0 + DIMC;
            float a0 = 0.f, a1 = 0.f, a2 = 0.f, a3 = 0.f;
            float b0 = 0.f, b1 = 0.f, b2 = 0.f, b3 = 0.f;
            #pragma unroll
            for (int c = 0; c < DIMC; c += 4) {
                a0 = fmaf(zr[c    ], e0[c    ], a0);
                a1 = fmaf(zr[c + 1], e0[c + 1], a1);
                a2 = fmaf(zr[c + 2], e0[c + 2], a2);
                a3 = fmaf(zr[c + 3], e0[c + 3], a3);
                b0 = fmaf(zr[c    ], e1[c    ], b0);
                b1 = fmaf(zr[c + 1], e1[c + 1], b1);
                b2 = fmaf(zr[c + 2], e1[c + 2], b2);
                b3 = fmaf(zr[c + 3], e1[c + 3], b3);
            }
            const int k = ch * CHUNK_K + kk;
            float s0 = sen[k]     - ((a0 + a1) + (a2 + a3));
            float s1 = sen[k + 1] - ((b0 + b1) + (b2 + b3));
            if (s0 < best) { best = s0; bidx = k; }
            if (s1 < best) { best = s1; bidx = k + 1; }
        }
    }

    // indices output (exact small int in f32)
    out[IDX_OFF + (size_t)b * TLEN + t] = (float)bidx;

    // quantized_st = z + (q - z), matching reference rounding; loss partial
    const float* __restrict__ eb = emb + (size_t)bidx * DIMC;
    float* qout = out + (size_t)b * (DIMC * TLEN) + t;
    float lsum = 0.f;
    #pragma unroll
    for (int c = 0; c < DIMC; ++c) {
        float q = eb[c];
        float d = q - zr[c];
        qout[(size_t)c * TLEN] = zr[c] + d;
        lsum = fmaf(d, d, lsum);
    }

    // segment sums via replicated atomics
    const int r = (int)((blockIdx.y * gridDim.x + blockIdx.x) % (unsigned)R);
    atomicAdd(cnt + (size_t)r * KB_NUM + bidx, 1.0f);
    float* es = esum + ((size_t)r * KB_NUM + bidx) * DIMC;
    #pragma unroll
    for (int c = 0; c < DIMC; ++c) atomicAdd(es + c, zr[c]);

    // wave-reduce loss, one atomic per wave
    #pragma unroll
    for (int off = 32; off > 0; off >>= 1)
        lsum += __shfl_down(lsum, off, 64);
    if ((threadIdx.x & 63) == 0) atomicAdd(lossAcc, lsum);
}

// ---------------------------------------------------------------------------
// Kernel 2: stats — new_cluster_size, n_tot, perplexity, loss
// single block of 512 threads (thread = code k)
// ---------------------------------------------------------------------------
__global__ __launch_bounds__(512) void vq_stats_kernel(
    const float* __restrict__ cluster_size,
    const float* __restrict__ cnt,
    const float* __restrict__ lossAcc,
    float* __restrict__ out,
    float* __restrict__ ntotp,   // [1] scratch
    int R)
{
    const int k = threadIdx.x;

    float n = 0.f;
    #pragma unroll 4
    for (int r = 0; r < R; ++r) n += cnt[(size_t)r * KB_NUM + k];

    float ncs = cluster_size[k] * DECAY_F + (1.0f - DECAY_F) * n;
    out[NCS_OFF + k] = ncs;

    __shared__ float red[KB_NUM];

    // n_tot = sum(new_cluster_size)
    red[k] = ncs;
    __syncthreads();
    for (int s = KB_NUM / 2; s > 0; s >>= 1) {
        if (k < s) red[k] += red[k + s];
        __syncthreads();
    }
    if (k == 0) ntotp[0] = red[0];
    __syncthreads();

    // perplexity over p = n/N
    float p = n * (1.0f / (float)NTOK);
    red[k] = p * logf(p + 1e-10f);
    __syncthreads();
    for (int s = KB_NUM / 2; s > 0; s >>= 1) {
        if (k < s) red[k] += red[k + s];
        __syncthreads();
    }
    if (k == 0) {
        out[PLEX_OFF] = expf(-red[0]);
        out[LOSS_OFF] = 0.25f * lossAcc[0] * (1.0f / (float)(BSZ * DIMC * TLEN));
    }
}

// ---------------------------------------------------------------------------
// Kernel 3: embedding update — grid = 512 blocks (one per code) x 64 threads
// ---------------------------------------------------------------------------
__global__ __launch_bounds__(64) void vq_embed_kernel(
    const float* __restrict__ embed_avg,
    const float* __restrict__ esum,
    const float* __restrict__ ntotp,
    float* __restrict__ out,
    int R)
{
    const int k = blockIdx.x;
    const int c = threadIdx.x;

    float es = 0.f;
    #pragma unroll 4
    for (int r = 0; r < R; ++r)
        es += esum[((size_t)r * KB_NUM + k) * DIMC + c];

    float nea = embed_avg[(size_t)k * DIMC + c] * DECAY_F + (1.0f - DECAY_F) * es;
    out[NEA_OFF + (size_t)k * DIMC + c] = nea;

    float ncs  = out[NCS_OFF + k];
    float ntot = ntotp[0];
    float denom = (ncs + EPS_F) / (ntot + (float)KB_NUM * EPS_F) * ntot;
    out[NEMB_OFF + (size_t)k * DIMC + c] = nea / denom;
}

// ---------------------------------------------------------------------------
extern "C" void kernel_launch(void* const* d_in, const int* in_sizes, int n_in,
                              void* d_out, int out_size, void* d_ws, size_t ws_size,
                              hipStream_t stream)
{
    const float* z            = (const float*)d_in[0];
    const float* emb          = (const float*)d_in[1];
    const float* cluster_size = (const float*)d_in[2];
    const float* embed_avg    = (const float*)d_in[3];
    float* out = (float*)d_out;

    char* ws = (char*)d_ws;
    float* lossAcc = (float*)ws;            // 1 f32
    float* ntotp   = (float*)(ws + 64);     // 1 f32
    float* enorm   = (float*)(ws + 256);    // 512 f32
    const size_t CNT_OFF = 4096;
    const size_t perR = (size_t)(KB_NUM + KB_NUM * DIMC) * sizeof(float); // 133120 B

    int R = 1;
    if (ws_size > CNT_OFF + perR)
        R = (int)((ws_size - CNT_OFF) / perR);
    if (R < 1) R = 1;
    if (R > 16) R = 16;

    float* cnt  = (float*)(ws + CNT_OFF);          // [R][KB_NUM]
    float* esum = cnt + (size_t)R * KB_NUM;        // [R][KB_NUM*DIMC]

    // zero accumulators (lossAcc + ntot + cnt + esum); enorm is fully rewritten
    hipMemsetAsync(d_ws, 0, CNT_OFF + (size_t)R * perR, stream);

    vq_enorm_kernel<<<dim3(2), dim3(256), 0, stream>>>(emb, enorm);

    dim3 grid(TLEN / 256, BSZ);
    vq_main_kernel<<<grid, dim3(256), 0, stream>>>(z, emb, enorm, out,
                                                   cnt, esum, lossAcc, R);

    vq_stats_kernel<<<dim3(1), dim3(512), 0, stream>>>(
        cluster_size, cnt, lossAcc, out, ntotp, R);

    vq_embed_kernel<<<dim3(KB_NUM), dim3(DIMC), 0, stream>>>(
        embed_avg, esum, ntotp, out, R);
}